// Round 18
// baseline (253.008 us; speedup 1.0000x reference)
//
#include <hip/hip_runtime.h>
#include <math.h>

#define CC 96
#define BB 512
#define TT 512

// ---------------------------------------------------------------------------
// Kernel 0: column max of transitions and E[i][j] = exp(T[i][j]-maxT[j])
// ---------------------------------------------------------------------------
__global__ __launch_bounds__(128) void crf_prep(const float* __restrict__ trans,
                                                float* __restrict__ E,
                                                float* __restrict__ maxT) {
    int j = threadIdx.x;
    if (j < CC) {
        float m = -INFINITY;
        for (int i = 0; i < CC; ++i) m = fmaxf(m, trans[i * CC + j]);
        maxT[j] = m;
        for (int i = 0; i < CC; ++i) E[i * CC + j] = __expf(trans[i * CC + j] - m);
    }
}

// ---------------------------------------------------------------------------
// Kernel 0b: pack mask rows into bit-words (no per-step SMEM loads).
// ---------------------------------------------------------------------------
__global__ __launch_bounds__(64) void pack_mask(const int* __restrict__ mask,
                                                unsigned* __restrict__ mbits) {
    const int b = blockIdx.x;
    const int w = threadIdx.x;
    if (w < 16) {
        unsigned bits = 0u;
        for (int k = 0; k < 32; ++k)
            bits |= (mask[b * TT + w * 32 + k] ? 1u : 0u) << k;
        mbits[b * 16 + w] = bits;
    }
}

// ---------------------------------------------------------------------------
// Kernel 1: forward recurrence, linear space, column-split, DS-pipe diet.
// r17 diagnosis: step ~1000cy == DS-pipe ISSUE time (~130 DS instrs/CU/step
// at ~6cy: b64 reads + shfl_xor16/32 which are ds_swizzle/bpermute + writes).
// VALUBusy only 41% -> DS-bound. Two changes, same structure:
//  (1) lane regroup g=l&3, jp=l>>2: the 4-partial cross-group reduce becomes
//      shfl_xor(1)+shfl_xor(2) = DPP quad_perm = VALU pipe, ZERO DS ops
//      (same reduction tree as r17 -> identical fp math).
//  (2) 6x ds_read_b128 broadcast reads per lane instead of 12x ds_read_b64
//      (broadcast reads are issue-limited; halves their pipe time).
// DS per CU per step: ~130 -> ~56 instrs. Barriers/renorm/prefetch unchanged.
// ---------------------------------------------------------------------------
#define PKFMA_LO(A_, S_, E_) \
    asm("v_pk_fma_f32 %0, %1, %2, %0 op_sel:[0,0,0] op_sel_hi:[0,1,1]" \
        : "+v"(A_) : "v"(S_), "v"(E_))
#define PKFMA_HI(A_, S_, E_) \
    asm("v_pk_fma_f32 %0, %1, %2, %0 op_sel:[1,0,0] op_sel_hi:[1,1,1]" \
        : "+v"(A_) : "v"(S_), "v"(E_))

#define STEP(PF_, K_, BIT_, REN_) do {                                        \
    const int sl_ = (K_) & 3;                                                 \
    const int pr_ = (K_) & 1;                                                 \
    const float2 ce_ = es[sl_];                                               \
    es[sl_] = *(const float2*)(PF_);                                          \
    const float scx_ = __expf(mTx + ce_.x);                                   \
    const float scy_ = __expf(mTy + ce_.y);                                   \
    float2 a0={0.f,0.f}, a1={0.f,0.f}, a2={0.f,0.f}, a3={0.f,0.f};            \
    const float* src_ = &pb[pr_][24 * g];                                     \
    _Pragma("unroll")                                                         \
    for (int k_ = 0; k_ < 24; k_ += 8) {                                      \
        const float4 q0_ = *(const float4*)(src_ + k_);                       \
        const float4 q1_ = *(const float4*)(src_ + k_ + 4);                   \
        const float2 pA_ = make_float2(q0_.x, q0_.y);                         \
        const float2 pB_ = make_float2(q0_.z, q0_.w);                         \
        const float2 pC_ = make_float2(q1_.x, q1_.y);                         \
        const float2 pD_ = make_float2(q1_.z, q1_.w);                         \
        PKFMA_LO(a0, pA_, er[k_]);                                            \
        PKFMA_HI(a1, pA_, er[k_ + 1]);                                        \
        PKFMA_LO(a2, pB_, er[k_ + 2]);                                        \
        PKFMA_HI(a3, pB_, er[k_ + 3]);                                        \
        PKFMA_LO(a0, pC_, er[k_ + 4]);                                        \
        PKFMA_HI(a1, pC_, er[k_ + 5]);                                        \
        PKFMA_LO(a2, pD_, er[k_ + 6]);                                        \
        PKFMA_HI(a3, pD_, er[k_ + 7]);                                        \
    }                                                                         \
    float qx_ = (a0.x + a1.x) + (a2.x + a3.x);                                \
    float qy_ = (a0.y + a1.y) + (a2.y + a3.y);                                \
    qx_ += __shfl_xor(qx_, 1); qx_ += __shfl_xor(qx_, 2);                     \
    qy_ += __shfl_xor(qy_, 1); qy_ += __shfl_xor(qy_, 2);                     \
    if (BIT_) { prx = qx_ * scx_; pry = qy_ * scy_; }                         \
    if (REN_) {                                                               \
        float loc_ = own ? (prx + pry) : 0.f;                                 \
        loc_ += __shfl_xor(loc_, 1); loc_ += __shfl_xor(loc_, 2);             \
        loc_ += __shfl_xor(loc_, 4); loc_ += __shfl_xor(loc_, 8);             \
        loc_ += __shfl_xor(loc_, 16); loc_ += __shfl_xor(loc_, 32);           \
        if (l == 0) wsum[w] = loc_;                                           \
        asm volatile("s_waitcnt lgkmcnt(0)" ::: "memory");                    \
        __builtin_amdgcn_s_barrier();                                         \
        const float r_ = (wsum[0] + wsum[1]) + (wsum[2] + wsum[3]);           \
        const float inv_ = 1.0f / r_;                                         \
        prx *= inv_; pry *= inv_;                                             \
        S += (double)__logf(r_);                                              \
    }                                                                         \
    if (own) *(float2*)&pb[pr_ ^ 1][j0] = make_float2(prx, pry);              \
    asm volatile("s_waitcnt lgkmcnt(0)" ::: "memory");                        \
    __builtin_amdgcn_s_barrier();                                             \
} while (0)

__global__ __launch_bounds__(256, 2)
void crf_forward(const float* __restrict__ emissions,
                 const unsigned* __restrict__ mbits,
                 const float* __restrict__ start_t,
                 const float* __restrict__ end_t,
                 const float* __restrict__ E,
                 const float* __restrict__ maxT,
                 float* __restrict__ log_den) {
    const int b = blockIdx.x;
    const int w = threadIdx.x >> 6;       // wave: owns j-columns 24w..24w+23
    const int l = threadIdx.x & 63;
    const int g = l & 3;                  // i-quarter group: i in [24g, 24g+24)
    const int jp = l >> 2;                // j-pair within wave (active < 12)
    const bool act = (jp < 12);
    const int jpc = act ? jp : 11;        // clamped
    const int j0 = 24 * w + 2 * jpc;      // global state pair base (<= 94)
    const bool own = (g == 0) && act;     // lanes that publish p

    __shared__ __align__(16) float pb[2][CC];   // broadcast p, by parity
    __shared__ float wsum[4];

    // E regs: er[k] = (E[i][j0], E[i][j0+1]), i = 24g + k  -> 48 VGPRs
    float2 er[24];
#pragma unroll
    for (int k = 0; k < 24; ++k)
        er[k] = *(const float2*)(E + (size_t)(24 * g + k) * CC + j0);

    const float* ep = emissions + (size_t)b * TT * CC + j0;
    const float mTx = maxT[j0];
    const float mTy = maxT[j0 + 1];

    // init t=0: p = exp(start + em0), replicated in all lanes of the pair
    float prx, pry;
    {
        const float2 e0 = *(const float2*)ep;
        prx = __expf(start_t[j0]     + e0.x);
        pry = __expf(start_t[j0 + 1] + e0.y);
    }
    double S = 0.0;
    if (own) *(float2*)&pb[1][j0] = make_float2(prx, pry);
    asm volatile("s_waitcnt lgkmcnt(0)" ::: "memory");
    __builtin_amdgcn_s_barrier();          // publish init (cross-wave reads)

    // emission prefetch slots: es[t&3] holds emission(t), t=1..4
    float2 es[4];
#pragma unroll
    for (int s = 1; s <= 4; ++s) es[s & 3] = *(const float2*)(ep + (size_t)s * CC);
    const float* pf = ep + (size_t)5 * CC;

    // head: t = 1..7
    const unsigned wb0 = mbits[b * 16];
#pragma unroll
    for (int k = 1; k < 8; ++k) {
        STEP(pf, k, (wb0 >> k) & 1u, 0);
        pf += CC;
    }
    // main: sb = 1..62 (t = 8*sb + k); renorm at k==0
    unsigned swc = wb0 >> 8;
    for (int sb = 1; sb < 63; ++sb) {
        const int sbn = sb + 1;
        const unsigned swn = mbits[b * 16 + (sbn >> 2)] >> ((sbn & 3) * 8);
#pragma unroll
        for (int k = 0; k < 8; ++k) {
            STEP(pf, k, (swc >> k) & 1u, k == 0);
            pf += CC;
        }
        swc = swn;
    }
    // tail: t = 504..511, prefetch clamped to t=511
#pragma unroll
    for (int k = 0; k < 8; ++k) {
        const int t_ = 504 + k;
        const int tn_ = (t_ + 4 <= TT - 1) ? (t_ + 4) : (TT - 1);
        STEP(ep + (size_t)tn_ * CC, k, (swc >> k) & 1u, k == 0);
    }

    // final: log_den = S + log(sum_j p[j] * exp(end[j]))
    float fx = own ? (prx * __expf(end_t[j0]) + pry * __expf(end_t[j0 + 1])) : 0.f;
#pragma unroll
    for (int off = 1; off < 64; off <<= 1) fx += __shfl_xor(fx, off);
    if (l == 0) wsum[w] = fx;
    __syncthreads();
    if (threadIdx.x == 0)
        log_den[b] = (float)(S + (double)__logf((wsum[0] + wsum[1]) + (wsum[2] + wsum[3])));
}

// ---------------------------------------------------------------------------
// Kernel 2: joint likelihood (numerator) — one block per batch.
// ---------------------------------------------------------------------------
__global__ __launch_bounds__(256) void crf_joint(const float* __restrict__ emissions,
                                                 const int* __restrict__ tags,
                                                 const int* __restrict__ mask,
                                                 const float* __restrict__ trans,
                                                 const float* __restrict__ start_t,
                                                 const float* __restrict__ end_t,
                                                 float* __restrict__ log_num) {
    const int b = blockIdx.x;
    const int tid = threadIdx.x;
    float s = 0.f;
    int mcount = 0;
    for (int t = tid; t < TT; t += 256) {
        int tg = tags[b * TT + t];
        float em = emissions[((size_t)b * TT + t) * CC + tg];
        int mk = mask[b * TT + t];
        mcount += mk;
        if (t == 0) {
            s += start_t[tg] + em;  // t=0 term unmasked in reference
        } else {
            int tp = tags[b * TT + t - 1];
            s += mk ? (trans[tp * CC + tg] + em) : 0.f;
        }
    }
    __shared__ float sred[4];
    __shared__ int mred[4];
#pragma unroll
    for (int off = 32; off; off >>= 1) {
        s += __shfl_xor(s, off);
        mcount += __shfl_xor(mcount, off);
    }
    if ((tid & 63) == 0) { sred[tid >> 6] = s; mred[tid >> 6] = mcount; }
    __syncthreads();
    if (tid == 0) {
        float tot = (sred[0] + sred[1]) + (sred[2] + sred[3]);
        int mt = (mred[0] + mred[1]) + (mred[2] + mred[3]);
        int last_tag = tags[b * TT + (mt - 1)];
        log_num[b] = tot + end_t[last_tag];
    }
}

// ---------------------------------------------------------------------------
// Kernel 3: final mean(log_den - log_num)
// ---------------------------------------------------------------------------
__global__ __launch_bounds__(512) void crf_final(const float* __restrict__ log_den,
                                                 const float* __restrict__ log_num,
                                                 float* __restrict__ out) {
    const int tid = threadIdx.x;
    float d = log_den[tid] - log_num[tid];
#pragma unroll
    for (int off = 32; off; off >>= 1) d += __shfl_xor(d, off);
    __shared__ float sred[8];
    if ((tid & 63) == 0) sred[tid >> 6] = d;
    __syncthreads();
    if (tid == 0) {
        float tot = 0.f;
        for (int w = 0; w < 8; ++w) tot += sred[w];
        out[0] = tot / (float)BB;
    }
}

extern "C" void kernel_launch(void* const* d_in, const int* in_sizes, int n_in,
                              void* d_out, int out_size, void* d_ws, size_t ws_size,
                              hipStream_t stream) {
    const float* emissions = (const float*)d_in[0];
    const int*   tags      = (const int*)d_in[1];
    const int*   mask      = (const int*)d_in[2];
    const float* trans     = (const float*)d_in[3];
    const float* start_t   = (const float*)d_in[4];
    const float* end_t     = (const float*)d_in[5];
    float* out = (float*)d_out;

    float*    ws      = (float*)d_ws;
    float*    E       = ws;               // 9216 floats
    float*    maxT    = ws + 9216;        // 96
    float*    log_den = ws + 9312;        // 512
    float*    log_num = ws + 9824;        // 512
    unsigned* mbits   = (unsigned*)(ws + 10336);  // 512*16 u32

    crf_prep<<<1, 128, 0, stream>>>(trans, E, maxT);
    pack_mask<<<BB, 64, 0, stream>>>(mask, mbits);
    crf_forward<<<BB, 256, 0, stream>>>(emissions, mbits, start_t, end_t, E, maxT, log_den);
    crf_joint<<<BB, 256, 0, stream>>>(emissions, tags, mask, trans, start_t, end_t, log_num);
    crf_final<<<1, 512, 0, stream>>>(log_den, log_num, out);
}

// Round 19
// 179.460 us; speedup vs baseline: 1.4098x; 1.4098x over previous
//
#include <hip/hip_runtime.h>
#include <math.h>

#define CC 96
#define BB 512
#define TT 512

// ---------------------------------------------------------------------------
// Kernel 0: column max of transitions and E[i][j] = exp(T[i][j]-maxT[j])
// ---------------------------------------------------------------------------
__global__ __launch_bounds__(128) void crf_prep(const float* __restrict__ trans,
                                                float* __restrict__ E,
                                                float* __restrict__ maxT) {
    int j = threadIdx.x;
    if (j < CC) {
        float m = -INFINITY;
        for (int i = 0; i < CC; ++i) m = fmaxf(m, trans[i * CC + j]);
        maxT[j] = m;
        for (int i = 0; i < CC; ++i) E[i * CC + j] = __expf(trans[i * CC + j] - m);
    }
}

// ---------------------------------------------------------------------------
// Kernel 0b: pack mask rows into bit-words (no per-step SMEM loads).
// ---------------------------------------------------------------------------
__global__ __launch_bounds__(64) void pack_mask(const int* __restrict__ mask,
                                                unsigned* __restrict__ mbits) {
    const int b = blockIdx.x;
    const int w = threadIdx.x;
    if (w < 16) {
        unsigned bits = 0u;
        for (int k = 0; k < 32; ++k)
            bits |= (mask[b * TT + w * 32 + k] ? 1u : 0u) << k;
        mbits[b * 16 + w] = bits;
    }
}

// ---------------------------------------------------------------------------
// Kernel 1: BIDIRECTIONAL forward algorithm. r17/r18 showed the per-step
// cost is pinned at ~1000cy by {publish round-trip + barrier + reduce}
// latency — so attack the SERIAL DEPTH instead. The recurrence
// p_t = diag(sc_t).E^T.p_{t-1} is associative:
//   Z = eend^T.p_511 = c_255^T.p_255,  c_{t-1} = E.(sc_t (.) c_t), c_511=eend
// (masked steps are identity in both directions). 1024 blocks: blocks
// 0..511 run the forward half (t=1..255, r14-verified structure, E columns);
// blocks 512..1023 run the backward half (t=511..256, same structure with
// E ROWS and scale-before-publish u = sc(.)c). Serial depth 511 -> 256 and
// 4 blocks/CU (4 waves/SIMD) of TLP to fill the latency floor.
// Per-wave step: 12 ds_read_b64 own-quarter + 24 pk_fma + pex exchange
// (ONE lgkm+barrier) + self-publish own quarter (same-wave, no barrier).
// Renorm every 8 steps via shfl (replicated); S in double.
// ---------------------------------------------------------------------------
#define PKFMA_LO(A_, S_, E_) \
    asm("v_pk_fma_f32 %0, %1, %2, %0 op_sel:[0,0,0] op_sel_hi:[0,1,1]" \
        : "+v"(A_) : "v"(S_), "v"(E_))
#define PKFMA_HI(A_, S_, E_) \
    asm("v_pk_fma_f32 %0, %1, %2, %0 op_sel:[1,0,0] op_sel_hi:[1,1,1]" \
        : "+v"(A_) : "v"(S_), "v"(E_))

// forward step (r14-verified): consume em_t, matvec p.E, scale-after
#define FSTEP(PF_, K_, BIT_, REN_) do {                                       \
    const int sl_ = (K_) & 3;                                                 \
    const int pr_ = (K_) & 1;                                                 \
    const float2 ce_ = es[sl_];                                               \
    es[sl_] = *(const float2*)(PF_);                                          \
    const float scx_ = __expf(mTx + ce_.x);                                   \
    const float scy_ = __expf(mTy + ce_.y);                                   \
    float2 a0={0.f,0.f}, a1={0.f,0.f}, a2={0.f,0.f}, a3={0.f,0.f};            \
    _Pragma("unroll")                                                         \
    for (int k_ = 0; k_ < 24; k_ += 4) {                                      \
        const float2 p0_ = *(const float2*)&pb[w][pr_][k_];                   \
        const float2 p1_ = *(const float2*)&pb[w][pr_][k_ + 2];               \
        PKFMA_LO(a0, p0_, ep2[k_]);                                           \
        PKFMA_HI(a1, p0_, ep2[k_ + 1]);                                       \
        PKFMA_LO(a2, p1_, ep2[k_ + 2]);                                       \
        PKFMA_HI(a3, p1_, ep2[k_ + 3]);                                       \
    }                                                                         \
    float2 mine_;                                                             \
    mine_.x = (a0.x + a1.x) + (a2.x + a3.x);                                  \
    mine_.y = (a0.y + a1.y) + (a2.y + a3.y);                                  \
    if (act) *(float2*)&pex[w][pr_][2 * l] = mine_;                           \
    asm volatile("s_waitcnt lgkmcnt(0)" ::: "memory");                        \
    __builtin_amdgcn_s_barrier();                                             \
    const float2 o0_ = *(const float2*)&pex[0][pr_][2 * lc];                  \
    const float2 o1_ = *(const float2*)&pex[1][pr_][2 * lc];                  \
    const float2 o2_ = *(const float2*)&pex[2][pr_][2 * lc];                  \
    const float2 o3_ = *(const float2*)&pex[3][pr_][2 * lc];                  \
    const float qx_ = (o0_.x + o1_.x) + (o2_.x + o3_.x);                      \
    const float qy_ = (o0_.y + o1_.y) + (o2_.y + o3_.y);                      \
    if (BIT_) { px = qx_ * scx_; py = qy_ * scy_; }                           \
    if (REN_) {                                                               \
        float r_ = px + py;                                                   \
        _Pragma("unroll")                                                     \
        for (int o_ = 32; o_; o_ >>= 1) r_ += __shfl_xor(r_, o_);             \
        const float inv_ = 1.0f / r_;                                         \
        px *= inv_; py *= inv_;                                               \
        S += (double)__logf(r_);                                              \
    }                                                                         \
    if (l >= wlo && l < whi)                                                  \
        *(float2*)&pb[w][pr_ ^ 1][2 * l - 24 * w] = make_float2(px, py);      \
} while (0)

// backward step: processing time t consumes em_{t-1}; matvec E.u with the
// PREVIOUSLY published u (= sc_t (.) c_t); masked update; publish next
// u = sc_{t-1} (.) c_{t-1} (scale-before). Same sync structure as FSTEP.
#define BSTEP(PF_, SL_, PR_, BIT_, REN_) do {                                 \
    const float2 ce_ = es[SL_];                                               \
    es[SL_] = *(const float2*)(PF_);                                          \
    float2 a0={0.f,0.f}, a1={0.f,0.f}, a2={0.f,0.f}, a3={0.f,0.f};            \
    _Pragma("unroll")                                                         \
    for (int k_ = 0; k_ < 24; k_ += 4) {                                      \
        const float2 u0_ = *(const float2*)&pb[w][PR_][k_];                   \
        const float2 u1_ = *(const float2*)&pb[w][PR_][k_ + 2];               \
        PKFMA_LO(a0, u0_, eb2[k_]);                                           \
        PKFMA_HI(a1, u0_, eb2[k_ + 1]);                                       \
        PKFMA_LO(a2, u1_, eb2[k_ + 2]);                                       \
        PKFMA_HI(a3, u1_, eb2[k_ + 3]);                                       \
    }                                                                         \
    float2 mine_;                                                             \
    mine_.x = (a0.x + a1.x) + (a2.x + a3.x);                                  \
    mine_.y = (a0.y + a1.y) + (a2.y + a3.y);                                  \
    if (act) *(float2*)&pex[w][PR_][2 * l] = mine_;                           \
    asm volatile("s_waitcnt lgkmcnt(0)" ::: "memory");                        \
    __builtin_amdgcn_s_barrier();                                             \
    const float2 o0_ = *(const float2*)&pex[0][PR_][2 * lc];                  \
    const float2 o1_ = *(const float2*)&pex[1][PR_][2 * lc];                  \
    const float2 o2_ = *(const float2*)&pex[2][PR_][2 * lc];                  \
    const float2 o3_ = *(const float2*)&pex[3][PR_][2 * lc];                  \
    const float qx_ = (o0_.x + o1_.x) + (o2_.x + o3_.x);                      \
    const float qy_ = (o0_.y + o1_.y) + (o2_.y + o3_.y);                      \
    if (act && (BIT_)) { cx = qx_; cy = qy_; }                                \
    if (REN_) {                                                               \
        float r_ = cx + cy;                                                   \
        _Pragma("unroll")                                                     \
        for (int o_ = 32; o_; o_ >>= 1) r_ += __shfl_xor(r_, o_);             \
        const float inv_ = 1.0f / r_;                                         \
        cx *= inv_; cy *= inv_;                                               \
        S += (double)__logf(r_);                                              \
    }                                                                         \
    if (l >= wlo && l < whi)                                                  \
        *(float2*)&pb[w][(PR_) ^ 1][2 * l - 24 * w] =                         \
            make_float2(__expf(mTx + ce_.x) * cx, __expf(mTy + ce_.y) * cy);  \
} while (0)

__global__ __launch_bounds__(256, 4)
void crf_half(const float* __restrict__ emissions,
              const unsigned* __restrict__ mbits,
              const float* __restrict__ start_t,
              const float* __restrict__ end_t,
              const float* __restrict__ E,
              const float* __restrict__ maxT,
              float* __restrict__ pmid, float* __restrict__ cmid,
              double* __restrict__ Sf, double* __restrict__ Sb) {
    const int dir = blockIdx.x >> 9;      // 0 = forward half, 1 = backward half
    const int b = blockIdx.x & 511;
    const int w = threadIdx.x >> 6;       // wave 0..3
    const int l = threadIdx.x & 63;
    const bool act = (l < 48);
    const int lc = act ? l : 47;
    const int s0 = 2 * lc;                // owned state pair
    const int wlo = 12 * w, whi = 12 * w + 12;

    __shared__ __align__(16) float pb[4][2][24];   // self-published quarters
    __shared__ __align__(16) float pex[4][2][CC];  // partial exchange

    const float* ep = emissions + (size_t)b * TT * CC + s0;
    const float mTx = act ? maxT[s0]     : -INFINITY;
    const float mTy = act ? maxT[s0 + 1] : -INFINITY;
    double S = 0.0;
    float2 es[4];

    if (dir == 0) {
        // ---------------- forward half: t = 1..255 ----------------
        float2 ep2[24];                    // E[i][s0], E[i][s0+1], i in wave quarter
#pragma unroll
        for (int k = 0; k < 24; ++k)
            ep2[k] = *(const float2*)(E + (size_t)(24 * w + k) * CC + s0);

        float px = 0.f, py = 0.f;
        {
            const float2 e0 = *(const float2*)ep;
            if (act) {
                px = __expf(start_t[s0]     + e0.x);
                py = __expf(start_t[s0 + 1] + e0.y);
            }
        }
        if (l >= wlo && l < whi)
            *(float2*)&pb[w][1][2 * l - 24 * w] = make_float2(px, py);

#pragma unroll
        for (int s = 1; s <= 4; ++s) es[s & 3] = *(const float2*)(ep + (size_t)s * CC);
        const float* pf = ep + (size_t)5 * CC;

        const unsigned wb0 = mbits[b * 16];
#pragma unroll
        for (int k = 1; k < 8; ++k) {
            FSTEP(pf, k, (wb0 >> k) & 1u, 0);
            pf += CC;
        }
        unsigned swc = wb0 >> 8;
        for (int sb = 1; sb < 32; ++sb) {
            const int sbn = sb + 1;
            const unsigned swn = mbits[b * 16 + (sbn >> 2)] >> ((sbn & 3) * 8);
#pragma unroll
            for (int k = 0; k < 8; ++k) {
                FSTEP(pf, k, (swc >> k) & 1u, k == 0);
                pf += CC;
            }
            swc = swn;
        }
        // state now = p_255 (renormalized), S = log-scale
        if (w == 0 && act) *(float2*)&pmid[(size_t)b * CC + s0] = make_float2(px, py);
        if (w == 0 && l == 0) Sf[b] = S;
    } else {
        // ---------------- backward half: t = 511..256 ----------------
        float2 eb2[24];                    // E[s0][j], E[s0+1][j], j in wave quarter
#pragma unroll
        for (int k = 0; k < 24; ++k)
            eb2[k] = make_float2(E[(size_t)s0 * CC + 24 * w + k],
                                 E[(size_t)(s0 + 1) * CC + 24 * w + k]);

        float cx = act ? __expf(end_t[s0])     : 0.f;
        float cy = act ? __expf(end_t[s0 + 1]) : 0.f;
        {   // initial publish: u_511 = sc_511 (.) c_511, into parity 0
            const float2 e511 = *(const float2*)(ep + (size_t)511 * CC);
            if (l >= wlo && l < whi)
                *(float2*)&pb[w][0][2 * l - 24 * w] =
                    make_float2(__expf(mTx + e511.x) * cx, __expf(mTy + e511.y) * cy);
        }
        // prefetch em stream m = t-1 descending: m = 510..507
#pragma unroll
        for (int s = 0; s < 4; ++s)
            es[(510 - s) & 3] = *(const float2*)(ep + (size_t)(510 - s) * CC);
        const float* pf = ep + (size_t)506 * CC;

        unsigned wv = mbits[b * 16 + 15] >> 24;          // bits t=504..511
        for (int grp = 63; grp >= 32; --grp) {
            const int gn = grp - 1;
            const unsigned wn = mbits[b * 16 + (gn >> 2)] >> ((gn & 3) * 8);
#pragma unroll
            for (int k = 0; k < 8; ++k) {                // t = 8*grp + 7 - k
                BSTEP(pf, (6 - k) & 3, k & 1, (wv >> (7 - k)) & 1u, k == 7);
                pf -= CC;
            }
            wv = wn;
        }
        // state now = c_255 (renormalized), S = log-scale
        if (w == 0 && act) *(float2*)&cmid[(size_t)b * CC + s0] = make_float2(cx, cy);
        if (w == 0 && l == 0) Sb[b] = S;
    }
}

// ---------------------------------------------------------------------------
// Kernel 1b: combine halves — log_den[b] = Sf + Sb + log(sum_j p[j]*c[j])
// ---------------------------------------------------------------------------
__global__ __launch_bounds__(64) void crf_combine(const float* __restrict__ pmid,
                                                  const float* __restrict__ cmid,
                                                  const double* __restrict__ Sf,
                                                  const double* __restrict__ Sb,
                                                  float* __restrict__ log_den) {
    const int b = blockIdx.x;
    const int l = threadIdx.x;
    float v = 0.f;
    if (l < 48) {
        const float2 p2 = *(const float2*)&pmid[(size_t)b * CC + 2 * l];
        const float2 c2 = *(const float2*)&cmid[(size_t)b * CC + 2 * l];
        v = p2.x * c2.x + p2.y * c2.y;
    }
#pragma unroll
    for (int off = 32; off; off >>= 1) v += __shfl_xor(v, off);
    if (l == 0) log_den[b] = (float)(Sf[b] + Sb[b] + (double)__logf(v));
}

// ---------------------------------------------------------------------------
// Kernel 2: joint likelihood (numerator) — one block per batch.
// ---------------------------------------------------------------------------
__global__ __launch_bounds__(256) void crf_joint(const float* __restrict__ emissions,
                                                 const int* __restrict__ tags,
                                                 const int* __restrict__ mask,
                                                 const float* __restrict__ trans,
                                                 const float* __restrict__ start_t,
                                                 const float* __restrict__ end_t,
                                                 float* __restrict__ log_num) {
    const int b = blockIdx.x;
    const int tid = threadIdx.x;
    float s = 0.f;
    int mcount = 0;
    for (int t = tid; t < TT; t += 256) {
        int tg = tags[b * TT + t];
        float em = emissions[((size_t)b * TT + t) * CC + tg];
        int mk = mask[b * TT + t];
        mcount += mk;
        if (t == 0) {
            s += start_t[tg] + em;  // t=0 term unmasked in reference
        } else {
            int tp = tags[b * TT + t - 1];
            s += mk ? (trans[tp * CC + tg] + em) : 0.f;
        }
    }
    __shared__ float sred[4];
    __shared__ int mred[4];
#pragma unroll
    for (int off = 32; off; off >>= 1) {
        s += __shfl_xor(s, off);
        mcount += __shfl_xor(mcount, off);
    }
    if ((tid & 63) == 0) { sred[tid >> 6] = s; mred[tid >> 6] = mcount; }
    __syncthreads();
    if (tid == 0) {
        float tot = (sred[0] + sred[1]) + (sred[2] + sred[3]);
        int mt = (mred[0] + mred[1]) + (mred[2] + mred[3]);
        int last_tag = tags[b * TT + (mt - 1)];
        log_num[b] = tot + end_t[last_tag];
    }
}

// ---------------------------------------------------------------------------
// Kernel 3: final mean(log_den - log_num)
// ---------------------------------------------------------------------------
__global__ __launch_bounds__(512) void crf_final(const float* __restrict__ log_den,
                                                 const float* __restrict__ log_num,
                                                 float* __restrict__ out) {
    const int tid = threadIdx.x;
    float d = log_den[tid] - log_num[tid];
#pragma unroll
    for (int off = 32; off; off >>= 1) d += __shfl_xor(d, off);
    __shared__ float sred[8];
    if ((tid & 63) == 0) sred[tid >> 6] = d;
    __syncthreads();
    if (tid == 0) {
        float tot = 0.f;
        for (int w = 0; w < 8; ++w) tot += sred[w];
        out[0] = tot / (float)BB;
    }
}

extern "C" void kernel_launch(void* const* d_in, const int* in_sizes, int n_in,
                              void* d_out, int out_size, void* d_ws, size_t ws_size,
                              hipStream_t stream) {
    const float* emissions = (const float*)d_in[0];
    const int*   tags      = (const int*)d_in[1];
    const int*   mask      = (const int*)d_in[2];
    const float* trans     = (const float*)d_in[3];
    const float* start_t   = (const float*)d_in[4];
    const float* end_t     = (const float*)d_in[5];
    float* out = (float*)d_out;

    float*    ws      = (float*)d_ws;
    float*    E       = ws;                         // 9216 f
    float*    maxT    = ws + 9216;                  // 96 f
    float*    log_den = ws + 9312;                  // 512 f
    float*    log_num = ws + 9824;                  // 512 f
    unsigned* mbits   = (unsigned*)(ws + 10336);    // 8192 u32
    float*    pmid    = ws + 18528;                 // 512*96 f
    float*    cmid    = ws + 67680;                 // 512*96 f
    double*   Sf      = (double*)(ws + 116832);     // 512 d (8B aligned)
    double*   Sb      = (double*)(ws + 117856);     // 512 d

    crf_prep<<<1, 128, 0, stream>>>(trans, E, maxT);
    pack_mask<<<BB, 64, 0, stream>>>(mask, mbits);
    crf_half<<<2 * BB, 256, 0, stream>>>(emissions, mbits, start_t, end_t, E, maxT,
                                         pmid, cmid, Sf, Sb);
    crf_combine<<<BB, 64, 0, stream>>>(pmid, cmid, Sf, Sb, log_den);
    crf_joint<<<BB, 256, 0, stream>>>(emissions, tags, mask, trans, start_t, end_t, log_num);
    crf_final<<<1, 512, 0, stream>>>(log_den, log_num, out);
}

// Round 20
// 177.324 us; speedup vs baseline: 1.4268x; 1.0120x over previous
//
#include <hip/hip_runtime.h>
#include <math.h>

#define CC 96
#define BB 512
#define TT 512

// ---------------------------------------------------------------------------
// Kernel 0: column max of transitions and E[i][j] = exp(T[i][j]-maxT[j])
// ---------------------------------------------------------------------------
__global__ __launch_bounds__(128) void crf_prep(const float* __restrict__ trans,
                                                float* __restrict__ E,
                                                float* __restrict__ maxT) {
    int j = threadIdx.x;
    if (j < CC) {
        float m = -INFINITY;
        for (int i = 0; i < CC; ++i) m = fmaxf(m, trans[i * CC + j]);
        maxT[j] = m;
        for (int i = 0; i < CC; ++i) E[i * CC + j] = __expf(trans[i * CC + j] - m);
    }
}

// ---------------------------------------------------------------------------
// Kernel 0b: pack mask rows into bit-words (no per-step SMEM loads).
// ---------------------------------------------------------------------------
__global__ __launch_bounds__(64) void pack_mask(const int* __restrict__ mask,
                                                unsigned* __restrict__ mbits) {
    const int b = blockIdx.x;
    const int w = threadIdx.x;
    if (w < 16) {
        unsigned bits = 0u;
        for (int k = 0; k < 32; ++k)
            bits |= (mask[b * TT + w * 32 + k] ? 1u : 0u) << k;
        mbits[b * 16 + w] = bits;
    }
}

// ---------------------------------------------------------------------------
// Kernel 1: BIDIRECTIONAL halves (r19, verified) with TWO-wave i-split
// blocks (r11's verified step shape). r19 measured: 4-wave split at 4
// blocks/CU -> 288 DS instrs/CU/step, 4-partial exchange, 4-wave barrier
// skew -> 1612 cyc/step. Now that bidirectional supplies TLP from the grid
// (1024 blocks = 4/CU), the narrower split wins: 2-partial exchange,
// 2-wave barrier, ~35% less DS traffic/CU. r11 demonstrated this step at
// 1133 cyc with ZERO TLP; at 2 waves/SIMD expect ~900-1100.
// Wave w owns i-half [48w, 48w+48) as 48 float2 E regs. Lane l owns state
// pair (2l, 2l+1), replicated in both waves. One lgkm+barrier per step.
// ---------------------------------------------------------------------------
#define PKFMA_LO(A_, S_, E_) \
    asm("v_pk_fma_f32 %0, %1, %2, %0 op_sel:[0,0,0] op_sel_hi:[0,1,1]" \
        : "+v"(A_) : "v"(S_), "v"(E_))
#define PKFMA_HI(A_, S_, E_) \
    asm("v_pk_fma_f32 %0, %1, %2, %0 op_sel:[1,0,0] op_sel_hi:[1,1,1]" \
        : "+v"(A_) : "v"(S_), "v"(E_))

// forward step: consume em_t, partial = p-half . E-half, exchange, scale-after
#define FSTEP(PF_, K_, BIT_, REN_) do {                                       \
    const int sl_ = (K_) & 3;                                                 \
    const int pr_ = (K_) & 1;                                                 \
    const float2 ce_ = es[sl_];                                               \
    es[sl_] = *(const float2*)(PF_);                                          \
    const float scx_ = __expf(mTx + ce_.x);                                   \
    const float scy_ = __expf(mTy + ce_.y);                                   \
    float2 a0={0.f,0.f}, a1={0.f,0.f}, a2={0.f,0.f}, a3={0.f,0.f};            \
    _Pragma("unroll")                                                         \
    for (int k_ = 0; k_ < 48; k_ += 4) {                                      \
        const float2 p0_ = *(const float2*)&pb[w][pr_][k_];                   \
        const float2 p1_ = *(const float2*)&pb[w][pr_][k_ + 2];               \
        PKFMA_LO(a0, p0_, ep2[k_]);                                           \
        PKFMA_HI(a1, p0_, ep2[k_ + 1]);                                       \
        PKFMA_LO(a2, p1_, ep2[k_ + 2]);                                       \
        PKFMA_HI(a3, p1_, ep2[k_ + 3]);                                       \
    }                                                                         \
    float2 mine_;                                                             \
    mine_.x = (a0.x + a1.x) + (a2.x + a3.x);                                  \
    mine_.y = (a0.y + a1.y) + (a2.y + a3.y);                                  \
    if (act) *(float2*)&pex[w][pr_][2 * l] = mine_;                           \
    asm volatile("s_waitcnt lgkmcnt(0)" ::: "memory");                        \
    __builtin_amdgcn_s_barrier();                                             \
    const float2 o0_ = *(const float2*)&pex[0][pr_][2 * lc];                  \
    const float2 o1_ = *(const float2*)&pex[1][pr_][2 * lc];                  \
    const float qx_ = o0_.x + o1_.x;                                          \
    const float qy_ = o0_.y + o1_.y;                                          \
    if (BIT_) { px = qx_ * scx_; py = qy_ * scy_; }                           \
    if (REN_) {                                                               \
        float r_ = px + py;                                                   \
        _Pragma("unroll")                                                     \
        for (int o_ = 32; o_; o_ >>= 1) r_ += __shfl_xor(r_, o_);             \
        const float inv_ = 1.0f / r_;                                         \
        px *= inv_; py *= inv_;                                               \
        S += (double)__logf(r_);                                              \
    }                                                                         \
    if (l >= wlo && l < whi)                                                  \
        *(float2*)&pb[w][pr_ ^ 1][2 * l - 48 * w] = make_float2(px, py);      \
} while (0)

// backward step: matvec E.u with previously published u = sc (.) c;
// masked update; publish next u scaled-before. Same sync structure.
#define BSTEP(PF_, SL_, PR_, BIT_, REN_) do {                                 \
    const float2 ce_ = es[SL_];                                               \
    es[SL_] = *(const float2*)(PF_);                                          \
    float2 a0={0.f,0.f}, a1={0.f,0.f}, a2={0.f,0.f}, a3={0.f,0.f};            \
    _Pragma("unroll")                                                         \
    for (int k_ = 0; k_ < 48; k_ += 4) {                                      \
        const float2 u0_ = *(const float2*)&pb[w][PR_][k_];                   \
        const float2 u1_ = *(const float2*)&pb[w][PR_][k_ + 2];               \
        PKFMA_LO(a0, u0_, eb2[k_]);                                           \
        PKFMA_HI(a1, u0_, eb2[k_ + 1]);                                       \
        PKFMA_LO(a2, u1_, eb2[k_ + 2]);                                       \
        PKFMA_HI(a3, u1_, eb2[k_ + 3]);                                       \
    }                                                                         \
    float2 mine_;                                                             \
    mine_.x = (a0.x + a1.x) + (a2.x + a3.x);                                  \
    mine_.y = (a0.y + a1.y) + (a2.y + a3.y);                                  \
    if (act) *(float2*)&pex[w][PR_][2 * l] = mine_;                           \
    asm volatile("s_waitcnt lgkmcnt(0)" ::: "memory");                        \
    __builtin_amdgcn_s_barrier();                                             \
    const float2 o0_ = *(const float2*)&pex[0][PR_][2 * lc];                  \
    const float2 o1_ = *(const float2*)&pex[1][PR_][2 * lc];                  \
    const float qx_ = o0_.x + o1_.x;                                          \
    const float qy_ = o0_.y + o1_.y;                                          \
    if (act && (BIT_)) { cx = qx_; cy = qy_; }                                \
    if (REN_) {                                                               \
        float r_ = cx + cy;                                                   \
        _Pragma("unroll")                                                     \
        for (int o_ = 32; o_; o_ >>= 1) r_ += __shfl_xor(r_, o_);             \
        const float inv_ = 1.0f / r_;                                         \
        cx *= inv_; cy *= inv_;                                               \
        S += (double)__logf(r_);                                              \
    }                                                                         \
    if (l >= wlo && l < whi)                                                  \
        *(float2*)&pb[w][(PR_) ^ 1][2 * l - 48 * w] =                         \
            make_float2(__expf(mTx + ce_.x) * cx, __expf(mTy + ce_.y) * cy);  \
} while (0)

__global__ __launch_bounds__(128, 1)
void crf_half(const float* __restrict__ emissions,
              const unsigned* __restrict__ mbits,
              const float* __restrict__ start_t,
              const float* __restrict__ end_t,
              const float* __restrict__ E,
              const float* __restrict__ maxT,
              float* __restrict__ pmid, float* __restrict__ cmid,
              double* __restrict__ Sf, double* __restrict__ Sb) {
    const int dir = blockIdx.x >> 9;      // 0 = forward half, 1 = backward half
    const int b = blockIdx.x & 511;
    const int w = threadIdx.x >> 6;       // wave 0/1: owns i-half [48w, 48w+48)
    const int l = threadIdx.x & 63;
    const bool act = (l < 48);
    const int lc = act ? l : 47;
    const int s0 = 2 * lc;                // owned state pair
    const int wlo = 24 * w, whi = 24 * w + 24;

    __shared__ __align__(16) float pb[2][2][48];   // self-published halves
    __shared__ __align__(16) float pex[2][2][CC];  // partial exchange

    const float* ep = emissions + (size_t)b * TT * CC + s0;
    const float mTx = act ? maxT[s0]     : -INFINITY;
    const float mTy = act ? maxT[s0 + 1] : -INFINITY;
    double S = 0.0;
    float2 es[4];

    if (dir == 0) {
        // ---------------- forward half: t = 1..255 ----------------
        float2 ep2[48];                    // E[i][s0], E[i][s0+1], i in wave half
#pragma unroll
        for (int k = 0; k < 48; ++k)
            ep2[k] = *(const float2*)(E + (size_t)(48 * w + k) * CC + s0);

        float px = 0.f, py = 0.f;
        {
            const float2 e0 = *(const float2*)ep;
            if (act) {
                px = __expf(start_t[s0]     + e0.x);
                py = __expf(start_t[s0 + 1] + e0.y);
            }
        }
        if (l >= wlo && l < whi)
            *(float2*)&pb[w][1][2 * l - 48 * w] = make_float2(px, py);

#pragma unroll
        for (int s = 1; s <= 4; ++s) es[s & 3] = *(const float2*)(ep + (size_t)s * CC);
        const float* pf = ep + (size_t)5 * CC;

        const unsigned wb0 = mbits[b * 16];
#pragma unroll
        for (int k = 1; k < 8; ++k) {
            FSTEP(pf, k, (wb0 >> k) & 1u, 0);
            pf += CC;
        }
        unsigned swc = wb0 >> 8;
        for (int sb = 1; sb < 32; ++sb) {
            const int sbn = sb + 1;
            const unsigned swn = mbits[b * 16 + (sbn >> 2)] >> ((sbn & 3) * 8);
#pragma unroll
            for (int k = 0; k < 8; ++k) {
                FSTEP(pf, k, (swc >> k) & 1u, k == 0);
                pf += CC;
            }
            swc = swn;
        }
        // state now = p_255 (renormalized), S = log-scale
        if (w == 0 && act) *(float2*)&pmid[(size_t)b * CC + s0] = make_float2(px, py);
        if (w == 0 && l == 0) Sf[b] = S;
    } else {
        // ---------------- backward half: t = 511..256 ----------------
        float2 eb2[48];                    // E[s0][j], E[s0+1][j], j in wave half
#pragma unroll
        for (int k = 0; k < 48; ++k)
            eb2[k] = make_float2(E[(size_t)s0 * CC + 48 * w + k],
                                 E[(size_t)(s0 + 1) * CC + 48 * w + k]);

        float cx = act ? __expf(end_t[s0])     : 0.f;
        float cy = act ? __expf(end_t[s0 + 1]) : 0.f;
        {   // initial publish: u_511 = sc_511 (.) c_511, into parity 0
            const float2 e511 = *(const float2*)(ep + (size_t)511 * CC);
            if (l >= wlo && l < whi)
                *(float2*)&pb[w][0][2 * l - 48 * w] =
                    make_float2(__expf(mTx + e511.x) * cx, __expf(mTy + e511.y) * cy);
        }
        // prefetch em stream m = t-1 descending: m = 510..507
#pragma unroll
        for (int s = 0; s < 4; ++s)
            es[(510 - s) & 3] = *(const float2*)(ep + (size_t)(510 - s) * CC);
        const float* pf = ep + (size_t)506 * CC;

        unsigned wv = mbits[b * 16 + 15] >> 24;          // bits t=504..511
        for (int grp = 63; grp >= 32; --grp) {
            const int gn = grp - 1;
            const unsigned wn = mbits[b * 16 + (gn >> 2)] >> ((gn & 3) * 8);
#pragma unroll
            for (int k = 0; k < 8; ++k) {                // t = 8*grp + 7 - k
                BSTEP(pf, (6 - k) & 3, k & 1, (wv >> (7 - k)) & 1u, k == 7);
                pf -= CC;
            }
            wv = wn;
        }
        // state now = c_255 (renormalized), S = log-scale
        if (w == 0 && act) *(float2*)&cmid[(size_t)b * CC + s0] = make_float2(cx, cy);
        if (w == 0 && l == 0) Sb[b] = S;
    }
}

// ---------------------------------------------------------------------------
// Kernel 1b: combine halves — log_den[b] = Sf + Sb + log(sum_j p[j]*c[j])
// ---------------------------------------------------------------------------
__global__ __launch_bounds__(64) void crf_combine(const float* __restrict__ pmid,
                                                  const float* __restrict__ cmid,
                                                  const double* __restrict__ Sf,
                                                  const double* __restrict__ Sb,
                                                  float* __restrict__ log_den) {
    const int b = blockIdx.x;
    const int l = threadIdx.x;
    float v = 0.f;
    if (l < 48) {
        const float2 p2 = *(const float2*)&pmid[(size_t)b * CC + 2 * l];
        const float2 c2 = *(const float2*)&cmid[(size_t)b * CC + 2 * l];
        v = p2.x * c2.x + p2.y * c2.y;
    }
#pragma unroll
    for (int off = 32; off; off >>= 1) v += __shfl_xor(v, off);
    if (l == 0) log_den[b] = (float)(Sf[b] + Sb[b] + (double)__logf(v));
}

// ---------------------------------------------------------------------------
// Kernel 2: joint likelihood (numerator) — one block per batch.
// ---------------------------------------------------------------------------
__global__ __launch_bounds__(256) void crf_joint(const float* __restrict__ emissions,
                                                 const int* __restrict__ tags,
                                                 const int* __restrict__ mask,
                                                 const float* __restrict__ trans,
                                                 const float* __restrict__ start_t,
                                                 const float* __restrict__ end_t,
                                                 float* __restrict__ log_num) {
    const int b = blockIdx.x;
    const int tid = threadIdx.x;
    float s = 0.f;
    int mcount = 0;
    for (int t = tid; t < TT; t += 256) {
        int tg = tags[b * TT + t];
        float em = emissions[((size_t)b * TT + t) * CC + tg];
        int mk = mask[b * TT + t];
        mcount += mk;
        if (t == 0) {
            s += start_t[tg] + em;  // t=0 term unmasked in reference
        } else {
            int tp = tags[b * TT + t - 1];
            s += mk ? (trans[tp * CC + tg] + em) : 0.f;
        }
    }
    __shared__ float sred[4];
    __shared__ int mred[4];
#pragma unroll
    for (int off = 32; off; off >>= 1) {
        s += __shfl_xor(s, off);
        mcount += __shfl_xor(mcount, off);
    }
    if ((tid & 63) == 0) { sred[tid >> 6] = s; mred[tid >> 6] = mcount; }
    __syncthreads();
    if (tid == 0) {
        float tot = (sred[0] + sred[1]) + (sred[2] + sred[3]);
        int mt = (mred[0] + mred[1]) + (mred[2] + mred[3]);
        int last_tag = tags[b * TT + (mt - 1)];
        log_num[b] = tot + end_t[last_tag];
    }
}

// ---------------------------------------------------------------------------
// Kernel 3: final mean(log_den - log_num)
// ---------------------------------------------------------------------------
__global__ __launch_bounds__(512) void crf_final(const float* __restrict__ log_den,
                                                 const float* __restrict__ log_num,
                                                 float* __restrict__ out) {
    const int tid = threadIdx.x;
    float d = log_den[tid] - log_num[tid];
#pragma unroll
    for (int off = 32; off; off >>= 1) d += __shfl_xor(d, off);
    __shared__ float sred[8];
    if ((tid & 63) == 0) sred[tid >> 6] = d;
    __syncthreads();
    if (tid == 0) {
        float tot = 0.f;
        for (int w = 0; w < 8; ++w) tot += sred[w];
        out[0] = tot / (float)BB;
    }
}

extern "C" void kernel_launch(void* const* d_in, const int* in_sizes, int n_in,
                              void* d_out, int out_size, void* d_ws, size_t ws_size,
                              hipStream_t stream) {
    const float* emissions = (const float*)d_in[0];
    const int*   tags      = (const int*)d_in[1];
    const int*   mask      = (const int*)d_in[2];
    const float* trans     = (const float*)d_in[3];
    const float* start_t   = (const float*)d_in[4];
    const float* end_t     = (const float*)d_in[5];
    float* out = (float*)d_out;

    float*    ws      = (float*)d_ws;
    float*    E       = ws;                         // 9216 f
    float*    maxT    = ws + 9216;                  // 96 f
    float*    log_den = ws + 9312;                  // 512 f
    float*    log_num = ws + 9824;                  // 512 f
    unsigned* mbits   = (unsigned*)(ws + 10336);    // 8192 u32
    float*    pmid    = ws + 18528;                 // 512*96 f
    float*    cmid    = ws + 67680;                 // 512*96 f
    double*   Sf      = (double*)(ws + 116832);     // 512 d (8B aligned)
    double*   Sb      = (double*)(ws + 117856);     // 512 d

    crf_prep<<<1, 128, 0, stream>>>(trans, E, maxT);
    pack_mask<<<BB, 64, 0, stream>>>(mask, mbits);
    crf_half<<<2 * BB, 128, 0, stream>>>(emissions, mbits, start_t, end_t, E, maxT,
                                         pmid, cmid, Sf, Sb);
    crf_combine<<<BB, 64, 0, stream>>>(pmid, cmid, Sf, Sb, log_den);
    crf_joint<<<BB, 256, 0, stream>>>(emissions, tags, mask, trans, start_t, end_t, log_num);
    crf_final<<<1, 512, 0, stream>>>(log_den, log_num, out);
}